// Round 1
// baseline (198.857 us; speedup 1.0000x reference)
//
#include <hip/hip_runtime.h>
#include <math.h>

// Problem: B=32, M=512, E=256, H=8, A=64. Rows R=B*M=16384, HA=512, groups G=H*B=256,
// group panel GP = M*A = 32768 elements.
//
// Pipeline (all f16 compute with fp32 MFMA accumulation; softmax in fp32):
//  1) cast x (fp32->f16)
//  2) transpose-cast W* to Wt[c][k] f16 (so GEMM B-frags are k-contiguous)
//  3) GEMM: Q,K,V (f16 out, natural 16384x512 layout), R = x@Wr (fp32 out)
//  4) per-group transposes: K panel [a][n] -> Ktg [n][a]; V panel [n][a] -> Vtg [a][n]
//  5) flash attention per (group, 128-row block), NC=64 chunks
//  6) finalize: head-mean + R + relu

typedef _Float16 f16;
typedef _Float16 f16x2 __attribute__((ext_vector_type(2)));
typedef _Float16 f16x4 __attribute__((ext_vector_type(4)));
typedef _Float16 f16x8 __attribute__((ext_vector_type(8)));
typedef float    f32x4 __attribute__((ext_vector_type(4)));

// ---------------- cast fp32 -> f16 (vectorized x4) ----------------
__global__ __launch_bounds__(256) void k_cast(const float* __restrict__ in,
                                              f16* __restrict__ out, int n4) {
  int i = blockIdx.x * 256 + threadIdx.x;
  if (i < n4) {
    f32x4 v = reinterpret_cast<const f32x4*>(in)[i];
    f16x4 h;
    h[0] = (f16)v[0]; h[1] = (f16)v[1]; h[2] = (f16)v[2]; h[3] = (f16)v[3];
    reinterpret_cast<f16x4*>(out)[i] = h;
  }
}

// ---------------- per-group 64x64-tile transpose (+cast to f16) ----------------
// in: groups of (R_ x C_) row-major; out: groups of (C_ x R_) row-major.
template <typename T>
__global__ __launch_bounds__(256) void k_transpose(const T* __restrict__ in,
                                                   f16* __restrict__ out,
                                                   int R_, int C_) {
  __shared__ f16 tile[64][68];  // pitch 68 (136B): paired writes conflict-free, reads ~4-way max
  int g = blockIdx.x;
  long gb = (long)g * R_ * C_;
  int r0 = blockIdx.y * 64, c0 = blockIdx.z * 64;
  int t = threadIdx.x;
#pragma unroll
  for (int u = 0; u < 8; ++u) {           // load 64x64 as pairs (coalesced)
    int e = u * 256 + t;
    int r = e >> 5, c = (e & 31) << 1;
    const T* p = in + gb + (long)(r0 + r) * C_ + (c0 + c);
    f16x2 v; v[0] = (f16)p[0]; v[1] = (f16)p[1];
    *reinterpret_cast<f16x2*>(&tile[r][c]) = v;
  }
  __syncthreads();
#pragma unroll
  for (int u = 0; u < 16; ++u) {          // store transposed (coalesced along r)
    int f = u * 256 + t;
    int cc = f >> 6, rr = f & 63;
    out[gb + (long)(c0 + cc) * R_ + (r0 + rr)] = tile[rr][cc];
  }
}

// ---------------- f16 MFMA GEMM: C(16384 x N) = Xh(16384x256) @ W (Wt is [c][k]) ----------------
// Block tile 128 x BN, 4 waves in 2x2, wave tile 64 x BN/2, 16x16x32 MFMA, BK=64 (4 K-iters).
template <int BN, bool F32OUT>
__global__ __launch_bounds__(256, 2) void k_gemm(const f16* __restrict__ Xh,
                                                 const f16* __restrict__ Wt,
                                                 f16* __restrict__ outH,
                                                 float* __restrict__ outF, int N) {
  __shared__ f16 Ash[128][72];   // pitch 72 (144B, 16B-aligned rows) -> 2-way max on b128
  __shared__ f16 Bsh[BN][72];
  constexpr int NT = BN / 32;
  int t = threadIdx.x;
  int w = t >> 6, l = t & 63;
  int lrow = l & 15, lg = l >> 4, lk8 = lg * 8;
  int wm = w >> 1, wn = w & 1;
  int rb = blockIdx.x * 128, cb = blockIdx.y * BN;

  f32x4 acc[4][NT] = {};

  for (int kt = 0; kt < 4; ++kt) {
    __syncthreads();
    int kb = kt * 64;
#pragma unroll
    for (int s = 0; s < 4; ++s) {           // stage A 128x64
      int row = s * 32 + (t >> 3), k0 = (t & 7) * 8;
      *reinterpret_cast<f16x8*>(&Ash[row][k0]) =
          *reinterpret_cast<const f16x8*>(Xh + (long)(rb + row) * 256 + kb + k0);
    }
#pragma unroll
    for (int s = 0; s < BN / 32; ++s) {     // stage B BNx64 (from Wt rows = output cols)
      int row = s * 32 + (t >> 3), k0 = (t & 7) * 8;
      *reinterpret_cast<f16x8*>(&Bsh[row][k0]) =
          *reinterpret_cast<const f16x8*>(Wt + (long)(cb + row) * 256 + kb + k0);
    }
    __syncthreads();

    f16x8 af[4][2];
#pragma unroll
    for (int mi = 0; mi < 4; ++mi)
#pragma unroll
      for (int ks = 0; ks < 2; ++ks)
        af[mi][ks] = *reinterpret_cast<const f16x8*>(&Ash[64 * wm + 16 * mi + lrow][32 * ks + lk8]);
#pragma unroll
    for (int nt = 0; nt < NT; ++nt) {
      f16x8 b0 = *reinterpret_cast<const f16x8*>(&Bsh[(BN / 2) * wn + 16 * nt + lrow][lk8]);
      f16x8 b1 = *reinterpret_cast<const f16x8*>(&Bsh[(BN / 2) * wn + 16 * nt + lrow][32 + lk8]);
#pragma unroll
      for (int mi = 0; mi < 4; ++mi) {
        acc[mi][nt] = __builtin_amdgcn_mfma_f32_16x16x32_f16(af[mi][0], b0, acc[mi][nt], 0, 0, 0);
        acc[mi][nt] = __builtin_amdgcn_mfma_f32_16x16x32_f16(af[mi][1], b1, acc[mi][nt], 0, 0, 0);
      }
    }
  }
  // epilogue: C/D layout row = 4*lg + r (+16*mi), col = lrow (+16*nt)
#pragma unroll
  for (int mi = 0; mi < 4; ++mi)
#pragma unroll
    for (int nt = 0; nt < NT; ++nt)
#pragma unroll
      for (int r = 0; r < 4; ++r) {
        int row = rb + 64 * wm + 16 * mi + 4 * lg + r;
        int col = cb + (BN / 2) * wn + 16 * nt + lrow;
        float v = acc[mi][nt][r];
        if constexpr (F32OUT) outF[(long)row * N + col] = v;
        else                  outH[(long)row * N + col] = (f16)v;
      }
}

// ---------------- flash attention per (group, 128-row block) ----------------
// Qh: flat panels [m][a]; Ktg: flat panels [n][a]; Vtg: flat panels [a][n]; Of: fp32 panels [m][a].
__global__ __launch_bounds__(256, 2) void k_attn(const f16* __restrict__ Qh,
                                                 const f16* __restrict__ Ktg,
                                                 const f16* __restrict__ Vtg,
                                                 float* __restrict__ Of) {
  __shared__ f16 Ksh[64][72];       // [n][a] chunk
  __shared__ f16 Vsh[64][72];       // [a][n] chunk
  __shared__ f16 Psh[4][32][72];    // per-wave P [m'][n]
  int g = blockIdx.x, mb = blockIdx.y;
  int t = threadIdx.x, w = t >> 6, l = t & 63;
  int lrow = l & 15, lg = l >> 4, lk8 = lg * 8;
  long gp = (long)g * 32768;
  const f16* Qg = Qh + gp;
  const f16* Kg = Ktg + gp;
  const f16* Vg = Vtg + gp;
  float* Og = Of + gp;
  int m0 = mb * 128 + w * 32;

  // Q A-fragments straight from global (A-frag: row = l&15, k = 8*(l>>4)+j contiguous)
  f16x8 qf[2][2];
#pragma unroll
  for (int mi = 0; mi < 2; ++mi)
#pragma unroll
    for (int ks = 0; ks < 2; ++ks)
      qf[mi][ks] = *reinterpret_cast<const f16x8*>(Qg + (long)(m0 + 16 * mi + lrow) * 64 + 32 * ks + lk8);

  f32x4 accO[2][4] = {};
  float Mx[2][4], Ls[2][4];
#pragma unroll
  for (int mi = 0; mi < 2; ++mi)
#pragma unroll
    for (int r = 0; r < 4; ++r) { Mx[mi][r] = -INFINITY; Ls[mi][r] = 0.f; }

  for (int c = 0; c < 8; ++c) {   // 8 chunks of 64 keys
    __syncthreads();
#pragma unroll
    for (int s = 0; s < 2; ++s) { // stage K chunk [n][a] and V chunk [a][n]
      int row = s * 32 + (t >> 3), o8 = (t & 7) * 8;
      *reinterpret_cast<f16x8*>(&Ksh[row][o8]) =
          *reinterpret_cast<const f16x8*>(Kg + (long)(c * 64 + row) * 64 + o8);
      *reinterpret_cast<f16x8*>(&Vsh[row][o8]) =
          *reinterpret_cast<const f16x8*>(Vg + (long)row * 512 + c * 64 + o8);
    }
    __syncthreads();

    // S = Q * K^T for this chunk: B-frag from Ksh[n][a] (k=a contiguous)
    f32x4 S[2][4] = {};
#pragma unroll
    for (int nt = 0; nt < 4; ++nt) {
      f16x8 k0 = *reinterpret_cast<const f16x8*>(&Ksh[16 * nt + lrow][lk8]);
      f16x8 k1 = *reinterpret_cast<const f16x8*>(&Ksh[16 * nt + lrow][32 + lk8]);
#pragma unroll
      for (int mi = 0; mi < 2; ++mi) {
        S[mi][nt] = __builtin_amdgcn_mfma_f32_16x16x32_f16(qf[mi][0], k0, S[mi][nt], 0, 0, 0);
        S[mi][nt] = __builtin_amdgcn_mfma_f32_16x16x32_f16(qf[mi][1], k1, S[mi][nt], 0, 0, 0);
      }
    }

    // online softmax; row (mi,r) lives in the 16 lanes of this lane-group (cols = 16*nt+lrow)
#pragma unroll
    for (int mi = 0; mi < 2; ++mi) {
#pragma unroll
      for (int r = 0; r < 4; ++r) {
        float tm = fmaxf(fmaxf(S[mi][0][r], S[mi][1][r]), fmaxf(S[mi][2][r], S[mi][3][r]));
        tm = fmaxf(tm, __shfl_xor(tm, 1));
        tm = fmaxf(tm, __shfl_xor(tm, 2));
        tm = fmaxf(tm, __shfl_xor(tm, 4));
        tm = fmaxf(tm, __shfl_xor(tm, 8));
        float nm = fmaxf(Mx[mi][r], tm);
        float sc = __expf(Mx[mi][r] - nm);   // first chunk: exp(-inf)=0
        Mx[mi][r] = nm;
#pragma unroll
        for (int at = 0; at < 4; ++at) accO[mi][at][r] *= sc;
        float pv[4]; float ps = 0.f;
#pragma unroll
        for (int nt = 0; nt < 4; ++nt) { pv[nt] = __expf(S[mi][nt][r] - nm); ps += pv[nt]; }
        ps += __shfl_xor(ps, 1); ps += __shfl_xor(ps, 2);
        ps += __shfl_xor(ps, 4); ps += __shfl_xor(ps, 8);
        Ls[mi][r] = Ls[mi][r] * sc + ps;
        // write P row to Psh as f16x2 by even lanes (avoids same-dword b16 write hazard)
        int mrow = 16 * mi + 4 * lg + r;
#pragma unroll
        for (int nt = 0; nt < 4; ++nt) {
          float pn = __shfl_xor(pv[nt], 1);
          if ((l & 1) == 0) {
            f16x2 p2; p2[0] = (f16)pv[nt]; p2[1] = (f16)pn;
            *reinterpret_cast<f16x2*>(&Psh[w][mrow][16 * nt + lrow]) = p2;
          }
        }
      }
    }

    // O += P * V : A-frag from Psh[m][n] (k=n contiguous), B-frag from Vsh[a][n] (k=n contiguous)
#pragma unroll
    for (int ks = 0; ks < 2; ++ks) {
      f16x8 pa[2];
#pragma unroll
      for (int mi = 0; mi < 2; ++mi)
        pa[mi] = *reinterpret_cast<const f16x8*>(&Psh[w][16 * mi + lrow][32 * ks + lk8]);
#pragma unroll
      for (int at = 0; at < 4; ++at) {
        f16x8 vb = *reinterpret_cast<const f16x8*>(&Vsh[16 * at + lrow][32 * ks + lk8]);
#pragma unroll
        for (int mi = 0; mi < 2; ++mi)
          accO[mi][at] = __builtin_amdgcn_mfma_f32_16x16x32_f16(pa[mi], vb, accO[mi][at], 0, 0, 0);
      }
    }
  }

  // epilogue: normalize and store fp32 per-head output (coalesced along a)
#pragma unroll
  for (int mi = 0; mi < 2; ++mi)
#pragma unroll
    for (int r = 0; r < 4; ++r) {
      float inv = 1.f / Ls[mi][r];
      int row = m0 + 16 * mi + 4 * lg + r;
#pragma unroll
      for (int at = 0; at < 4; ++at)
        Og[(long)row * 64 + 16 * at + lrow] = accO[mi][at][r] * inv;
    }
}

// ---------------- finalize: head-mean + R + relu ----------------
__global__ __launch_bounds__(256) void k_finalize(const float* __restrict__ Of,
                                                  const float* __restrict__ Rf,
                                                  float* __restrict__ out) {
  int i = blockIdx.x * 256 + threadIdx.x;  // f32x4 index over 1048576 elements
  f32x4 s = {};
#pragma unroll
  for (int h = 0; h < 8; ++h) {
    f32x4 o = reinterpret_cast<const f32x4*>(Of + (long)h * 1048576)[i];
    s += o;
  }
  f32x4 r = reinterpret_cast<const f32x4*>(Rf)[i];
  f32x4 v = s * 0.125f + r;
#pragma unroll
  for (int j = 0; j < 4; ++j) v[j] = v[j] > 0.f ? v[j] : 0.f;
  reinterpret_cast<f32x4*>(out)[i] = v;
}

extern "C" void kernel_launch(void* const* d_in, const int* in_sizes, int n_in,
                              void* d_out, int out_size, void* d_ws, size_t ws_size,
                              hipStream_t stream) {
  const float* x  = (const float*)d_in[0];
  const float* Wq = (const float*)d_in[1];
  const float* Wk = (const float*)d_in[2];
  const float* Wv = (const float*)d_in[3];
  const float* Wr = (const float*)d_in[4];
  float* out = (float*)d_out;
  char* w = (char*)d_ws;

  // workspace layout (bytes); total ~93 MiB. Of overlays Kn+Vn (dead after transposes).
  f16*   Xh  = (f16*)(w + 0);           // 16384*256*2   = 8,388,608
  f16*   Wqt = (f16*)(w + 8388608);     // 512*256*2     =   262,144
  f16*   Wkt = (f16*)(w + 8650752);
  f16*   Wvt = (f16*)(w + 8912896);
  f16*   Wrt = (f16*)(w + 9175040);     // 64*256*2      =    32,768
  f16*   Qh  = (f16*)(w + 9207808);     // 16384*512*2   = 16,777,216
  f16*   Kn  = (f16*)(w + 25985024);
  f16*   Vn  = (f16*)(w + 42762240);
  f16*   Ktg = (f16*)(w + 59539456);
  f16*   Vtg = (f16*)(w + 76316672);
  float* Rf  = (float*)(w + 93093888);  // 16384*64*4    =  4,194,304
  float* Of  = (float*)(w + 25985024);  // overlay (32 MiB over Kn+Vn)

  // 1) casts / weight transposes
  k_cast<<<4096, 256, 0, stream>>>(x, Xh, 1048576);
  k_transpose<float><<<dim3(1, 4, 8), 256, 0, stream>>>(Wq, Wqt, 256, 512);
  k_transpose<float><<<dim3(1, 4, 8), 256, 0, stream>>>(Wk, Wkt, 256, 512);
  k_transpose<float><<<dim3(1, 4, 8), 256, 0, stream>>>(Wv, Wvt, 256, 512);
  k_transpose<float><<<dim3(1, 4, 1), 256, 0, stream>>>(Wr, Wrt, 256, 64);

  // 2) projections
  k_gemm<128, false><<<dim3(128, 4), 256, 0, stream>>>(Xh, Wqt, Qh, nullptr, 512);
  k_gemm<128, false><<<dim3(128, 4), 256, 0, stream>>>(Xh, Wkt, Kn, nullptr, 512);
  k_gemm<128, false><<<dim3(128, 4), 256, 0, stream>>>(Xh, Wvt, Vn, nullptr, 512);
  k_gemm<64, true><<<dim3(128, 1), 256, 0, stream>>>(Xh, Wrt, nullptr, Rf, 64);

  // 3) per-group K/V transposes: K panels (64x512)->(512x64) i.e. [n][a]; V panels (512x64)->(64x512) i.e. [a][n]
  k_transpose<f16><<<dim3(256, 1, 8), 256, 0, stream>>>(Kn, Ktg, 64, 512);
  k_transpose<f16><<<dim3(256, 8, 1), 256, 0, stream>>>(Vn, Vtg, 512, 64);

  // 4) attention
  k_attn<<<dim3(256, 4), 256, 0, stream>>>(Qh, Ktg, Vtg, Of);

  // 5) head-mean + R + relu
  k_finalize<<<1024, 256, 0, stream>>>(Of, Rf, out);
}

// Round 2
// 153.297 us; speedup vs baseline: 1.2972x; 1.2972x over previous
//
#include <hip/hip_runtime.h>
#include <math.h>

// B=32, M=512, E=256, H=8, A=64. Rows R=B*M=16384, groups G=H*B=256, panel=32768.
// Pipeline: cast x->f16; fused W transpose-cast; ONE fused QKV GEMM (N=1536) + R GEMM;
// per-group K/V transposes; swapped-QK^T flash attention (wave-parallel softmax);
// finalize head-mean + R + relu.

typedef _Float16 f16;
typedef _Float16 f16x2 __attribute__((ext_vector_type(2)));
typedef _Float16 f16x4 __attribute__((ext_vector_type(4)));
typedef _Float16 f16x8 __attribute__((ext_vector_type(8)));
typedef float    f32x4 __attribute__((ext_vector_type(4)));

// ---------------- cast fp32 -> f16 (x4) ----------------
__global__ __launch_bounds__(256) void k_cast(const float* __restrict__ in,
                                              f16* __restrict__ out, int n4) {
  int i = blockIdx.x * 256 + threadIdx.x;
  if (i < n4) {
    f32x4 v = reinterpret_cast<const f32x4*>(in)[i];
    f16x4 h;
    h[0] = (f16)v[0]; h[1] = (f16)v[1]; h[2] = (f16)v[2]; h[3] = (f16)v[3];
    reinterpret_cast<f16x4*>(out)[i] = h;
  }
}

// ---------------- fused weight transpose-cast: Wq|Wk|Wv -> Wt[1536][256], Wr -> Wrt[64][256] ----------------
__global__ __launch_bounds__(256) void k_transpose_w(const float* __restrict__ Wq,
                                                     const float* __restrict__ Wk,
                                                     const float* __restrict__ Wv,
                                                     const float* __restrict__ Wr,
                                                     f16* __restrict__ Wt,
                                                     f16* __restrict__ Wrt) {
  __shared__ f16 tile[64][68];
  int b = blockIdx.x;
  const float* src; f16* dst; int r0, c0, Cin;
  if (b < 96) {
    int ws = b >> 5, rem = b & 31;
    src = (ws == 0) ? Wq : (ws == 1) ? Wk : Wv;
    dst = Wt + ws * 512 * 256;
    Cin = 512; r0 = (rem >> 3) * 64; c0 = (rem & 7) * 64;
  } else {
    src = Wr; dst = Wrt; Cin = 64; r0 = (b - 96) * 64; c0 = 0;
  }
  int t = threadIdx.x;
#pragma unroll
  for (int u = 0; u < 8; ++u) {
    int e = u * 256 + t;
    int r = e >> 5, c = (e & 31) << 1;
    const float* p = src + (long)(r0 + r) * Cin + (c0 + c);
    f16x2 v; v[0] = (f16)p[0]; v[1] = (f16)p[1];
    *reinterpret_cast<f16x2*>(&tile[r][c]) = v;
  }
  __syncthreads();
#pragma unroll
  for (int u = 0; u < 16; ++u) {
    int f = u * 256 + t;
    int cc = f >> 6, rr = f & 63;
    dst[(long)(c0 + cc) * 256 + (r0 + rr)] = tile[rr][cc];
  }
}

// ---------------- per-group 64x64-tile transpose (f16->f16) ----------------
__global__ __launch_bounds__(256) void k_transpose(const f16* __restrict__ in,
                                                   f16* __restrict__ out,
                                                   int R_, int C_) {
  __shared__ f16 tile[64][68];
  int g = blockIdx.x;
  long gb = (long)g * R_ * C_;
  int r0 = blockIdx.y * 64, c0 = blockIdx.z * 64;
  int t = threadIdx.x;
#pragma unroll
  for (int u = 0; u < 8; ++u) {
    int e = u * 256 + t;
    int r = e >> 5, c = (e & 31) << 1;
    const f16* p = in + gb + (long)(r0 + r) * C_ + (c0 + c);
    f16x2 v; v[0] = p[0]; v[1] = p[1];
    *reinterpret_cast<f16x2*>(&tile[r][c]) = v;
  }
  __syncthreads();
#pragma unroll
  for (int u = 0; u < 16; ++u) {
    int f = u * 256 + t;
    int cc = f >> 6, rr = f & 63;
    out[gb + (long)(c0 + cc) * R_ + (r0 + rr)] = tile[rr][cc];
  }
}

// ---------------- f16 MFMA GEMM: C(16384 x N) = Xh(16384x256) @ Wt ([c][k]) ----------------
// F32OUT=false: fused QKV path — output col>>9 selects contiguous buffer (Qh|Kn|Vn), 2^23 elems apart.
template <int BN, bool F32OUT>
__global__ __launch_bounds__(256, 2) void k_gemm(const f16* __restrict__ Xh,
                                                 const f16* __restrict__ Wt,
                                                 f16* __restrict__ outH,
                                                 float* __restrict__ outF, int N) {
  __shared__ f16 Ash[128][72];
  __shared__ f16 Bsh[BN][72];
  constexpr int NT = BN / 32;
  int t = threadIdx.x;
  int w = t >> 6, l = t & 63;
  int lrow = l & 15, lg = l >> 4, lk8 = lg * 8;
  int wm = w >> 1, wn = w & 1;
  int rb = blockIdx.x * 128, cb = blockIdx.y * BN;

  f32x4 acc[4][NT] = {};

  for (int kt = 0; kt < 4; ++kt) {
    __syncthreads();
    int kb = kt * 64;
#pragma unroll
    for (int s = 0; s < 4; ++s) {
      int row = s * 32 + (t >> 3), k0 = (t & 7) * 8;
      *reinterpret_cast<f16x8*>(&Ash[row][k0]) =
          *reinterpret_cast<const f16x8*>(Xh + (long)(rb + row) * 256 + kb + k0);
    }
#pragma unroll
    for (int s = 0; s < BN / 32; ++s) {
      int row = s * 32 + (t >> 3), k0 = (t & 7) * 8;
      *reinterpret_cast<f16x8*>(&Bsh[row][k0]) =
          *reinterpret_cast<const f16x8*>(Wt + (long)(cb + row) * 256 + kb + k0);
    }
    __syncthreads();

    f16x8 af[4][2];
#pragma unroll
    for (int mi = 0; mi < 4; ++mi)
#pragma unroll
      for (int ks = 0; ks < 2; ++ks)
        af[mi][ks] = *reinterpret_cast<const f16x8*>(&Ash[64 * wm + 16 * mi + lrow][32 * ks + lk8]);
#pragma unroll
    for (int nt = 0; nt < NT; ++nt) {
      f16x8 b0 = *reinterpret_cast<const f16x8*>(&Bsh[(BN / 2) * wn + 16 * nt + lrow][lk8]);
      f16x8 b1 = *reinterpret_cast<const f16x8*>(&Bsh[(BN / 2) * wn + 16 * nt + lrow][32 + lk8]);
#pragma unroll
      for (int mi = 0; mi < 4; ++mi) {
        acc[mi][nt] = __builtin_amdgcn_mfma_f32_16x16x32_f16(af[mi][0], b0, acc[mi][nt], 0, 0, 0);
        acc[mi][nt] = __builtin_amdgcn_mfma_f32_16x16x32_f16(af[mi][1], b1, acc[mi][nt], 0, 0, 0);
      }
    }
  }
#pragma unroll
  for (int mi = 0; mi < 4; ++mi)
#pragma unroll
    for (int nt = 0; nt < NT; ++nt)
#pragma unroll
      for (int r = 0; r < 4; ++r) {
        int row = rb + 64 * wm + 16 * mi + 4 * lg + r;
        int col = cb + (BN / 2) * wn + 16 * nt + lrow;
        float v = acc[mi][nt][r];
        if constexpr (F32OUT) {
          outF[(long)row * N + col] = v;
        } else {
          long idx = ((long)(col >> 9) << 23) + (long)row * 512 + (col & 511);
          outH[idx] = (f16)v;
        }
      }
}

// ---------------- flash attention, swapped QK^T (wave-parallel softmax) ----------------
// Qh panels [m][a]; Ktg panels [n][a]; Vtg panels [a][n]; Of f16 panels [m][a].
__global__ __launch_bounds__(256, 4) void k_attn(const f16* __restrict__ Qh,
                                                 const f16* __restrict__ Ktg,
                                                 const f16* __restrict__ Vtg,
                                                 f16* __restrict__ Of) {
  __shared__ f16 Ksh[64][72];       // [n][a] chunk
  __shared__ f16 Vsh[64][72];       // [a][n] chunk
  __shared__ f16 Psh[4][32][72];    // per-wave P [qrow'][key']
  int g = blockIdx.x, mb = blockIdx.y;
  int t = threadIdx.x, w = t >> 6, l = t & 63;
  int lrow = l & 15, lg = l >> 4, lk8 = lg * 8;
  long gp = (long)g * 32768;
  const f16* Qg = Qh + gp;
  const f16* Kg = Ktg + gp;
  const f16* Vg = Vtg + gp;
  f16* Og = Of + gp;
  int m0 = mb * 128 + w * 32;

  // Q as B-operand: lane needs Q[qrow=16mi+lrow][a=8lg+j+32ks] — contiguous from global.
  f16x8 qf[2][2];
#pragma unroll
  for (int mi = 0; mi < 2; ++mi)
#pragma unroll
    for (int ks = 0; ks < 2; ++ks)
      qf[mi][ks] = *reinterpret_cast<const f16x8*>(Qg + (long)(m0 + 16 * mi + lrow) * 64 + 32 * ks + lk8);

  f32x4 accO[2][4] = {};
  float Mx[2] = {-INFINITY, -INFINITY}, Ls[2] = {0.f, 0.f};

  for (int c = 0; c < 8; ++c) {
    __syncthreads();
#pragma unroll
    for (int s = 0; s < 2; ++s) {
      int row = s * 32 + (t >> 3), o8 = (t & 7) * 8;
      *reinterpret_cast<f16x8*>(&Ksh[row][o8]) =
          *reinterpret_cast<const f16x8*>(Kg + (long)(c * 64 + row) * 64 + o8);
      *reinterpret_cast<f16x8*>(&Vsh[row][o8]) =
          *reinterpret_cast<const f16x8*>(Vg + (long)row * 512 + c * 64 + o8);
    }
    __syncthreads();

    // S^T = K · Q^T : A-frag = K[key][a], B-frag = Q[qrow][a].
    // Output St[mi][nt]: reg r -> key = 16nt + 4lg + r, qrow = 16mi + lrow.
    f32x4 St[2][4] = {};
#pragma unroll
    for (int nt = 0; nt < 4; ++nt) {
      f16x8 k0 = *reinterpret_cast<const f16x8*>(&Ksh[16 * nt + lrow][lk8]);
      f16x8 k1 = *reinterpret_cast<const f16x8*>(&Ksh[16 * nt + lrow][32 + lk8]);
#pragma unroll
      for (int mi = 0; mi < 2; ++mi) {
        St[mi][nt] = __builtin_amdgcn_mfma_f32_16x16x32_f16(k0, qf[mi][0], St[mi][nt], 0, 0, 0);
        St[mi][nt] = __builtin_amdgcn_mfma_f32_16x16x32_f16(k1, qf[mi][1], St[mi][nt], 0, 0, 0);
      }
    }

    // Wave-parallel online softmax: lane owns qrow = 16mi + lrow; keys split across lg.
    float scb[2][4];
#pragma unroll
    for (int mi = 0; mi < 2; ++mi) {
      float tm = St[mi][0][0];
#pragma unroll
      for (int nt = 0; nt < 4; ++nt)
#pragma unroll
        for (int r = 0; r < 4; ++r) tm = fmaxf(tm, St[mi][nt][r]);
      tm = fmaxf(tm, __shfl_xor(tm, 16));
      tm = fmaxf(tm, __shfl_xor(tm, 32));
      float nm = fmaxf(Mx[mi], tm);
      float sc = __expf(Mx[mi] - nm);     // chunk 0: exp(-inf)=0
      Mx[mi] = nm;
      float ps = 0.f;
#pragma unroll
      for (int nt = 0; nt < 4; ++nt)
#pragma unroll
        for (int r = 0; r < 4; ++r) {
          float p = __expf(St[mi][nt][r] - nm);
          St[mi][nt][r] = p;
          ps += p;
        }
      ps += __shfl_xor(ps, 16);
      ps += __shfl_xor(ps, 32);
      Ls[mi] = Ls[mi] * sc + ps;
      // P[qrow][key] -> Psh: r=0..3 are contiguous cols -> one b64 write per nt.
#pragma unroll
      for (int nt = 0; nt < 4; ++nt) {
        f16x4 p4;
        p4[0] = (f16)St[mi][nt][0]; p4[1] = (f16)St[mi][nt][1];
        p4[2] = (f16)St[mi][nt][2]; p4[3] = (f16)St[mi][nt][3];
        *reinterpret_cast<f16x4*>(&Psh[w][16 * mi + lrow][16 * nt + 4 * lg]) = p4;
      }
      // Redistribute sc from lane-layout (qrow=16mi+lrow) to acc-layout (qrow=16mi+4lg+r):
      // source lane 20*lg + r has lrow = 4*lg + r.
#pragma unroll
      for (int r = 0; r < 4; ++r) scb[mi][r] = __shfl(sc, 20 * lg + r);
    }
    // Rescale accumulator before adding this chunk's PV.
#pragma unroll
    for (int mi = 0; mi < 2; ++mi)
#pragma unroll
      for (int at = 0; at < 4; ++at)
#pragma unroll
        for (int r = 0; r < 4; ++r) accO[mi][at][r] *= scb[mi][r];

    // O += P · V : A-frag = P[qrow][key] from own wave's Psh (no barrier needed),
    // B-frag = V[key][a] from Vsh[a][key].
#pragma unroll
    for (int ks = 0; ks < 2; ++ks) {
      f16x8 pa[2];
#pragma unroll
      for (int mi = 0; mi < 2; ++mi)
        pa[mi] = *reinterpret_cast<const f16x8*>(&Psh[w][16 * mi + lrow][32 * ks + lk8]);
#pragma unroll
      for (int at = 0; at < 4; ++at) {
        f16x8 vb = *reinterpret_cast<const f16x8*>(&Vsh[16 * at + lrow][32 * ks + lk8]);
#pragma unroll
        for (int mi = 0; mi < 2; ++mi)
          accO[mi][at] = __builtin_amdgcn_mfma_f32_16x16x32_f16(pa[mi], vb, accO[mi][at], 0, 0, 0);
      }
    }
  }

  // Epilogue: redistribute 1/L the same way, normalize, store f16.
#pragma unroll
  for (int mi = 0; mi < 2; ++mi) {
    float inv = 1.f / Ls[mi];
    float invb[4];
#pragma unroll
    for (int r = 0; r < 4; ++r) invb[r] = __shfl(inv, 20 * lg + r);
#pragma unroll
    for (int r = 0; r < 4; ++r) {
      int row = m0 + 16 * mi + 4 * lg + r;
#pragma unroll
      for (int at = 0; at < 4; ++at)
        Og[(long)row * 64 + 16 * at + lrow] = (f16)(accO[mi][at][r] * invb[r]);
    }
  }
}

// ---------------- finalize: head-mean + R + relu ----------------
__global__ __launch_bounds__(256) void k_finalize(const f16* __restrict__ Of,
                                                  const float* __restrict__ Rf,
                                                  float* __restrict__ out) {
  int i = blockIdx.x * 256 + threadIdx.x;  // f16x4/f32x4 index over 1048576 elements
  f32x4 s = {};
#pragma unroll
  for (int h = 0; h < 8; ++h) {
    f16x4 o = reinterpret_cast<const f16x4*>(Of + (long)h * 1048576)[i];
#pragma unroll
    for (int j = 0; j < 4; ++j) s[j] += (float)o[j];
  }
  f32x4 r = reinterpret_cast<const f32x4*>(Rf)[i];
  f32x4 v = s * 0.125f + r;
#pragma unroll
  for (int j = 0; j < 4; ++j) v[j] = v[j] > 0.f ? v[j] : 0.f;
  reinterpret_cast<f32x4*>(out)[i] = v;
}

extern "C" void kernel_launch(void* const* d_in, const int* in_sizes, int n_in,
                              void* d_out, int out_size, void* d_ws, size_t ws_size,
                              hipStream_t stream) {
  const float* x  = (const float*)d_in[0];
  const float* Wq = (const float*)d_in[1];
  const float* Wk = (const float*)d_in[2];
  const float* Wv = (const float*)d_in[3];
  const float* Wr = (const float*)d_in[4];
  float* out = (float*)d_out;
  char* w = (char*)d_ws;

  // workspace layout (bytes):
  f16*   Xh  = (f16*)(w + 0);           // 8,388,608
  f16*   Wt  = (f16*)(w + 8388608);     // 1536*256*2 = 786,432
  f16*   Wrt = (f16*)(w + 9175040);     // 32,768
  f16*   Qh  = (f16*)(w + 9207808);     // Qh|Kn|Vn contiguous, 3 x 16,777,216
  f16*   Kn  = (f16*)(w + 25985024);
  f16*   Vn  = (f16*)(w + 42762240);
  f16*   Ktg = (f16*)(w + 59539456);    // 16,777,216
  f16*   Vtg = (f16*)(w + 76316672);    // 16,777,216
  float* Rf  = (float*)(w + 93093888);  // 4,194,304
  f16*   Of  = (f16*)(w + 25985024);    // overlay over Kn (dead after transposes), 16,777,216

  k_cast<<<4096, 256, 0, stream>>>(x, Xh, 1048576);
  k_transpose_w<<<100, 256, 0, stream>>>(Wq, Wk, Wv, Wr, Wt, Wrt);

  k_gemm<128, false><<<dim3(128, 12), 256, 0, stream>>>(Xh, Wt, Qh, nullptr, 1536);
  k_gemm<64, true><<<dim3(128, 1), 256, 0, stream>>>(Xh, Wrt, nullptr, Rf, 64);

  // K panels (64x512)->[n][a]; V panels (512x64)->[a][n]
  k_transpose<<<dim3(256, 1, 8), 256, 0, stream>>>(Kn, Ktg, 64, 512);
  k_transpose<<<dim3(256, 8, 1), 256, 0, stream>>>(Vn, Vtg, 512, 64);

  k_attn<<<dim3(256, 4), 256, 0, stream>>>(Qh, Ktg, Vtg, Of);
  k_finalize<<<1024, 256, 0, stream>>>(Of, Rf, out);
}